// Round 18
// baseline (517.540 us; speedup 1.0000x reference)
//
#include <hip/hip_runtime.h>
#include <hip/hip_bf16.h>

typedef __attribute__((ext_vector_type(8))) short bf16x8;
typedef __attribute__((ext_vector_type(4))) float f32x4;
typedef unsigned short ushort;

// bf16 element offsets inside the converted-weight buffer wb
#define OFF_QKV 0
#define OFF_WO  786432
#define OFF_W1  1048576
#define OFF_W2  2097152
#define OFF_AW1 3145728
#define OFF_CW  3211264
#define OFF_DW1 3276800
#define OFF_TW1 3407872
#define WB_TOTAL 3473408

__device__ inline float gelu_f(float x) {
    return 0.5f * x * (1.0f + erff(x * 0.70710678118654752f));
}

// fast tanh-form GELU (disto only): |err| <= ~1e-3 vs exact
__device__ inline float gelu_fast(float x) {
    float z = 0.79788456080286536f * fmaf(0.044715f * x * x, x, x);
    float e = __expf(2.0f * z);
    float th = 1.0f - 2.0f / (e + 1.0f);   // overflow-safe tanh
    return 0.5f * x * (1.0f + th);
}

__device__ inline ushort f2bfu(float x) {
    __hip_bfloat16 b = __float2bfloat16(x);
    return *reinterpret_cast<ushort*>(&b);
}

__device__ inline float blo(unsigned u) { return __uint_as_float(u << 16); }
__device__ inline float bhi(unsigned u) { return __uint_as_float(u & 0xffff0000u); }

__device__ inline uint4 pack_bf8(float4 a, float4 b) {
    uint4 p;
    p.x = f2bfu(a.x) | ((unsigned)f2bfu(a.y) << 16);
    p.y = f2bfu(a.z) | ((unsigned)f2bfu(a.w) << 16);
    p.z = f2bfu(b.x) | ((unsigned)f2bfu(b.y) << 16);
    p.w = f2bfu(b.z) | ((unsigned)f2bfu(b.w) << 16);
    return p;
}

__device__ inline float wave_sum(float v) {
#pragma unroll
    for (int o = 32; o > 0; o >>= 1) v += __shfl_xor(v, o);
    return v;
}
__device__ inline float wave_max(float v) {
#pragma unroll
    for (int o = 32; o > 0; o >>= 1) v = fmaxf(v, __shfl_xor(v, o));
    return v;
}

// ---------------- weight conversion ----------------
__global__ void convw_k(const float* __restrict__ Wqkv, const float* __restrict__ Wo,
                        const float* __restrict__ W1, const float* __restrict__ W2,
                        const float* __restrict__ aW1, const float* __restrict__ cW,
                        const float* __restrict__ dW1, const float* __restrict__ tW1,
                        ushort* __restrict__ dst) {
    size_t i = ((size_t)blockIdx.x * 256 + threadIdx.x) * 8;
    if (i >= WB_TOTAL) return;
    const float* src;
    size_t off;
    if (i < OFF_WO)        { src = Wqkv; off = i; }
    else if (i < OFF_W1)   { src = Wo;   off = i - OFF_WO; }
    else if (i < OFF_W2)   { src = W1;   off = i - OFF_W1; }
    else if (i < OFF_AW1)  { src = W2;   off = i - OFF_W2; }
    else if (i < OFF_CW)   { src = aW1;  off = i - OFF_AW1; }
    else if (i < OFF_DW1)  { src = cW;   off = i - OFF_CW; }
    else if (i < OFF_TW1)  { src = dW1;  off = i - OFF_DW1; }
    else                   { src = tW1;  off = i - OFF_TW1; }
    float4 f0 = *(const float4*)&src[off];
    float4 f1 = *(const float4*)&src[off + 4];
    *(uint4*)&dst[i] = pack_bf8(f0, f1);
}

// ---------------- embedding + positional encoding ----------------
__global__ void embed_k(const int* __restrict__ tokens, const float* __restrict__ emb,
                        float* __restrict__ x, ushort* __restrict__ xb) {
    int n = blockIdx.x, t = threadIdx.x;
    float e = emb[(size_t)tokens[n] * 256 + t];
    int k = t >> 1;
    float div = expf((float)(2 * k) * (-9.210340371976184f / 256.0f));
    float arg = (float)n * div;
    float v = e + ((t & 1) ? cosf(arg) : sinf(arg));
    x[(size_t)n * 256 + t] = v;
    xb[(size_t)n * 256 + t] = f2bfu(v);
}

// ---------------- MFMA GEMM, bf16 in / {f32 or bf16} out (64x64 tile) ----------------
template <int ACT, int OBF>
__global__ __launch_bounds__(256) void gemm_bf(const ushort* __restrict__ A,
                                               const ushort* __restrict__ Wb,
                                               const float* __restrict__ bias,
                                               float* __restrict__ C,
                                               ushort* __restrict__ Cb,
                                               int Nn, int K, int lda, int ldw, int koff,
                                               size_t woff, size_t boff) {
    __shared__ ushort Al[2][2048];
    __shared__ ushort Wl[2][2048];
    const int t = threadIdx.x;
    const int bm = blockIdx.y * 64, bn = blockIdx.x * 64;
    const int lane = t & 63, wv = t >> 6;
    const int lo = lane & 15, hi = lane >> 4;

    const ushort* aptr = A + (size_t)(bm + lane) * lda + wv * 8;
    const ushort* wptr = Wb + woff + (size_t)(bn + lane) * ldw + koff + wv * 8;

    f32x4 acc0 = {0.f, 0.f, 0.f, 0.f}, acc1 = acc0, acc2 = acc0, acc3 = acc0;
    uint4 a = *(const uint4*)aptr;
    uint4 w = *(const uint4*)wptr;
    const int nsteps = K >> 5;
    for (int s = 0; s < nsteps; ++s) {
        const int buf = s & 1;
        *(uint4*)&Al[buf][t * 8] = a;
        *(uint4*)&Wl[buf][t * 8] = w;
        __syncthreads();
        if (s + 1 < nsteps) {
            a = *(const uint4*)(aptr + (s + 1) * 32);
            w = *(const uint4*)(wptr + (s + 1) * 32);
        }
        bf16x8 af = *(bf16x8*)&Al[buf][(hi * 64 + wv * 16 + lo) * 8];
        bf16x8 b0 = *(bf16x8*)&Wl[buf][(hi * 64 + 0 + lo) * 8];
        bf16x8 b1 = *(bf16x8*)&Wl[buf][(hi * 64 + 16 + lo) * 8];
        bf16x8 b2 = *(bf16x8*)&Wl[buf][(hi * 64 + 32 + lo) * 8];
        bf16x8 b3 = *(bf16x8*)&Wl[buf][(hi * 64 + 48 + lo) * 8];
        acc0 = __builtin_amdgcn_mfma_f32_16x16x32_bf16(af, b0, acc0, 0, 0, 0);
        acc1 = __builtin_amdgcn_mfma_f32_16x16x32_bf16(af, b1, acc1, 0, 0, 0);
        acc2 = __builtin_amdgcn_mfma_f32_16x16x32_bf16(af, b2, acc2, 0, 0, 0);
        acc3 = __builtin_amdgcn_mfma_f32_16x16x32_bf16(af, b3, acc3, 0, 0, 0);
    }

    float bv0 = bias ? bias[boff + bn + 0 + lo] : 0.0f;
    float bv1 = bias ? bias[boff + bn + 16 + lo] : 0.0f;
    float bv2 = bias ? bias[boff + bn + 32 + lo] : 0.0f;
    float bv3 = bias ? bias[boff + bn + 48 + lo] : 0.0f;
#pragma unroll
    for (int r = 0; r < 4; ++r) {
        size_t rw = (size_t)(bm + wv * 16 + hi * 4 + r) * Nn + bn;
        float v0 = acc0[r] + bv0, v1 = acc1[r] + bv1, v2 = acc2[r] + bv2, v3 = acc3[r] + bv3;
        if (ACT == 1) {
            v0 = fmaxf(v0, 0.f); v1 = fmaxf(v1, 0.f); v2 = fmaxf(v2, 0.f); v3 = fmaxf(v3, 0.f);
        }
        if (ACT == 2) {
            v0 = gelu_f(v0); v1 = gelu_f(v1); v2 = gelu_f(v2); v3 = gelu_f(v3);
        }
        if (OBF) {
            Cb[rw + 0 + lo] = f2bfu(v0);
            Cb[rw + 16 + lo] = f2bfu(v1);
            Cb[rw + 32 + lo] = f2bfu(v2);
            Cb[rw + 48 + lo] = f2bfu(v3);
        } else {
            C[rw + 0 + lo] = v0;
            C[rw + 16 + lo] = v1;
            C[rw + 32 + lo] = v2;
            C[rw + 48 + lo] = v3;
        }
    }
}

// ---------------- FUSED: LN(x+y) prologue + FFN1 GEMM (+ReLU, bf16 out) ----------------
// Grid (16, 8): 16 n-blocks x 8 m-blocks. Each block computes LN for its 64 rows
// locally (redundant across n-blocks, cheap); blockIdx.x==0 publishes f32 LN to xn.
__global__ __launch_bounds__(256) void ffn1_ln_k(const float* __restrict__ x,
                                                 const float* __restrict__ y,
                                                 const float* __restrict__ g,
                                                 const float* __restrict__ bln,
                                                 const ushort* __restrict__ Wb,
                                                 const float* __restrict__ b1,
                                                 float* __restrict__ xn,
                                                 ushort* __restrict__ Cb,
                                                 size_t goff, size_t w1off, size_t b1off) {
    __shared__ ushort Afull[32 * 64 * 8];  // 32KB: LN'd A tile, [dblk(32)][row(64)] chunks
    __shared__ ushort Wl[2][2048];         // 8KB
    __shared__ float red[64][4];
    const int t = threadIdx.x;
    const int bm = blockIdx.y * 64, bn = blockIdx.x * 64;

    // ---- prologue: LN(x+y) for rows bm..bm+63 ----
    const int prow = t >> 2, pq = t & 3;
    const float* xr = x + (size_t)(bm + prow) * 256 + pq * 64;
    const float* yr = y + (size_t)(bm + prow) * 256 + pq * 64;
    float part = 0.f;
#pragma unroll
    for (int c = 0; c < 64; c += 4) {
        float4 a = *(const float4*)&xr[c];
        float4 b = *(const float4*)&yr[c];
        part += ((a.x + b.x) + (a.y + b.y)) + ((a.z + b.z) + (a.w + b.w));
    }
    red[prow][pq] = part;
    __syncthreads();
    float mean = ((red[prow][0] + red[prow][1]) + (red[prow][2] + red[prow][3])) * (1.0f / 256.0f);
    float p2 = 0.f;
#pragma unroll
    for (int c = 0; c < 64; c += 4) {
        float4 a = *(const float4*)&xr[c];
        float4 b = *(const float4*)&yr[c];
        float d0 = a.x + b.x - mean, d1 = a.y + b.y - mean;
        float d2 = a.z + b.z - mean, d3 = a.w + b.w - mean;
        p2 = fmaf(d0, d0, p2); p2 = fmaf(d1, d1, p2);
        p2 = fmaf(d2, d2, p2); p2 = fmaf(d3, d3, p2);
    }
    __syncthreads();
    red[prow][pq] = p2;
    __syncthreads();
    float var = ((red[prow][0] + red[prow][1]) + (red[prow][2] + red[prow][3])) * (1.0f / 256.0f);
    float inv = rsqrtf(var + 1e-5f);
#pragma unroll
    for (int c = 0; c < 64; c += 8) {
        int col = pq * 64 + c;
        float4 a0 = *(const float4*)&xr[c];
        float4 b0 = *(const float4*)&yr[c];
        float4 a1 = *(const float4*)&xr[c + 4];
        float4 b1v = *(const float4*)&yr[c + 4];
        float4 g0 = *(const float4*)&g[goff + col];
        float4 g1 = *(const float4*)&g[goff + col + 4];
        float4 l0 = *(const float4*)&bln[goff + col];
        float4 l1 = *(const float4*)&bln[goff + col + 4];
        float4 r0, r1;
        r0.x = (a0.x + b0.x - mean) * inv * g0.x + l0.x;
        r0.y = (a0.y + b0.y - mean) * inv * g0.y + l0.y;
        r0.z = (a0.z + b0.z - mean) * inv * g0.z + l0.z;
        r0.w = (a0.w + b0.w - mean) * inv * g0.w + l0.w;
        r1.x = (a1.x + b1v.x - mean) * inv * g1.x + l1.x;
        r1.y = (a1.y + b1v.y - mean) * inv * g1.y + l1.y;
        r1.z = (a1.z + b1v.z - mean) * inv * g1.z + l1.z;
        r1.w = (a1.w + b1v.w - mean) * inv * g1.w + l1.w;
        uint4 pk = pack_bf8(r0, r1);
        *(uint4*)&Afull[((col >> 3) * 64 + prow) * 8] = pk;
        if (blockIdx.x == 0) {
            *(float4*)&xn[(size_t)(bm + prow) * 256 + col] = r0;
            *(float4*)&xn[(size_t)(bm + prow) * 256 + col + 4] = r1;
        }
    }
    __syncthreads();

    // ---- K-loop: W double-buffered, A from Afull ----
    const int lane = t & 63, wv = t >> 6;
    const int lo = lane & 15, hi = lane >> 4;
    const ushort* wptr = Wb + w1off + (size_t)(bn + lane) * 256 + wv * 8;
    f32x4 acc0 = {0.f, 0.f, 0.f, 0.f}, acc1 = acc0, acc2 = acc0, acc3 = acc0;
    uint4 w = *(const uint4*)wptr;
    for (int s = 0; s < 8; ++s) {
        const int buf = s & 1;
        *(uint4*)&Wl[buf][t * 8] = w;
        __syncthreads();
        if (s < 7) w = *(const uint4*)(wptr + (s + 1) * 32);
        bf16x8 af = *(bf16x8*)&Afull[((s * 4 + hi) * 64 + wv * 16 + lo) * 8];
        bf16x8 b0 = *(bf16x8*)&Wl[buf][(hi * 64 + 0 + lo) * 8];
        bf16x8 b1 = *(bf16x8*)&Wl[buf][(hi * 64 + 16 + lo) * 8];
        bf16x8 b2 = *(bf16x8*)&Wl[buf][(hi * 64 + 32 + lo) * 8];
        bf16x8 b3 = *(bf16x8*)&Wl[buf][(hi * 64 + 48 + lo) * 8];
        acc0 = __builtin_amdgcn_mfma_f32_16x16x32_bf16(af, b0, acc0, 0, 0, 0);
        acc1 = __builtin_amdgcn_mfma_f32_16x16x32_bf16(af, b1, acc1, 0, 0, 0);
        acc2 = __builtin_amdgcn_mfma_f32_16x16x32_bf16(af, b2, acc2, 0, 0, 0);
        acc3 = __builtin_amdgcn_mfma_f32_16x16x32_bf16(af, b3, acc3, 0, 0, 0);
    }

    float bv0 = b1[b1off + bn + 0 + lo];
    float bv1 = b1[b1off + bn + 16 + lo];
    float bv2 = b1[b1off + bn + 32 + lo];
    float bv3 = b1[b1off + bn + 48 + lo];
#pragma unroll
    for (int r = 0; r < 4; ++r) {
        size_t rw = (size_t)(bm + wv * 16 + hi * 4 + r) * 1024 + bn;
        Cb[rw + 0 + lo] = f2bfu(fmaxf(acc0[r] + bv0, 0.f));
        Cb[rw + 16 + lo] = f2bfu(fmaxf(acc1[r] + bv1, 0.f));
        Cb[rw + 32 + lo] = f2bfu(fmaxf(acc2[r] + bv2, 0.f));
        Cb[rw + 48 + lo] = f2bfu(fmaxf(acc3[r] + bv3, 0.f));
    }
}

// ---------------- FFN2 split-K: grid (4, 8, 4); slice z covers K in [z*256, z*256+256) ----------------
__global__ __launch_bounds__(256) void ffn2_splitk(const ushort* __restrict__ A,
                                                   const ushort* __restrict__ Wb,
                                                   float* __restrict__ yp,
                                                   size_t woff) {
    __shared__ ushort Al[2][2048];
    __shared__ ushort Wl[2][2048];
    const int t = threadIdx.x;
    const int bm = blockIdx.y * 64, bn = blockIdx.x * 64;
    const int ks = blockIdx.z;
    const int lane = t & 63, wv = t >> 6;
    const int lo = lane & 15, hi = lane >> 4;

    const ushort* aptr = A + (size_t)(bm + lane) * 1024 + ks * 256 + wv * 8;
    const ushort* wptr = Wb + woff + (size_t)(bn + lane) * 1024 + ks * 256 + wv * 8;

    f32x4 acc0 = {0.f, 0.f, 0.f, 0.f}, acc1 = acc0, acc2 = acc0, acc3 = acc0;
    uint4 a = *(const uint4*)aptr;
    uint4 w = *(const uint4*)wptr;
    for (int s = 0; s < 8; ++s) {
        const int buf = s & 1;
        *(uint4*)&Al[buf][t * 8] = a;
        *(uint4*)&Wl[buf][t * 8] = w;
        __syncthreads();
        if (s < 7) {
            a = *(const uint4*)(aptr + (s + 1) * 32);
            w = *(const uint4*)(wptr + (s + 1) * 32);
        }
        bf16x8 af = *(bf16x8*)&Al[buf][(hi * 64 + wv * 16 + lo) * 8];
        bf16x8 b0 = *(bf16x8*)&Wl[buf][(hi * 64 + 0 + lo) * 8];
        bf16x8 b1 = *(bf16x8*)&Wl[buf][(hi * 64 + 16 + lo) * 8];
        bf16x8 b2 = *(bf16x8*)&Wl[buf][(hi * 64 + 32 + lo) * 8];
        bf16x8 b3 = *(bf16x8*)&Wl[buf][(hi * 64 + 48 + lo) * 8];
        acc0 = __builtin_amdgcn_mfma_f32_16x16x32_bf16(af, b0, acc0, 0, 0, 0);
        acc1 = __builtin_amdgcn_mfma_f32_16x16x32_bf16(af, b1, acc1, 0, 0, 0);
        acc2 = __builtin_amdgcn_mfma_f32_16x16x32_bf16(af, b2, acc2, 0, 0, 0);
        acc3 = __builtin_amdgcn_mfma_f32_16x16x32_bf16(af, b3, acc3, 0, 0, 0);
    }

    float* yo = yp + (size_t)ks * 131072;
#pragma unroll
    for (int r = 0; r < 4; ++r) {
        size_t rw = (size_t)(bm + wv * 16 + hi * 4 + r) * 256 + bn;
        yo[rw + 0 + lo] = acc0[r];
        yo[rw + 16 + lo] = acc1[r];
        yo[rw + 32 + lo] = acc2[r];
        yo[rw + 48 + lo] = acc3[r];
    }
}

// ---------------- residual + LayerNorm over 4 split-K slices + bias (xin -> xout,xb) ----------------
__global__ void ln_res4_k(const float* __restrict__ xin, const float* __restrict__ yp,
                          const float* __restrict__ b2, size_t b2off,
                          const float* __restrict__ g, const float* __restrict__ b,
                          size_t goff, float* __restrict__ xout, ushort* __restrict__ xb) {
    int row = blockIdx.x, t = threadIdx.x;
    __shared__ float red[8];
    size_t idx = (size_t)row * 256 + t;
    float v = xin[idx] + ((yp[idx] + yp[idx + 131072]) + (yp[idx + 262144] + yp[idx + 393216]))
            + b2[b2off + t];
    float s = wave_sum(v);
    if ((t & 63) == 0) red[t >> 6] = s;
    __syncthreads();
    float mean = (red[0] + red[1] + red[2] + red[3]) * (1.0f / 256.0f);
    float d = v - mean;
    float s2 = wave_sum(d * d);
    if ((t & 63) == 0) red[4 + (t >> 6)] = s2;
    __syncthreads();
    float var = (red[4] + red[5] + red[6] + red[7]) * (1.0f / 256.0f);
    float res = d * rsqrtf(var + 1e-5f) * g[goff + t] + b[goff + t];
    xout[idx] = res;
    xb[idx] = f2bfu(res);
}

// ---------------- batched head GEMMs: z = {contact-h, disto-U, disto-V, torsion-t1} ----------------
__global__ __launch_bounds__(256) void heads_k(const ushort* __restrict__ A,
                                               const ushort* __restrict__ Wb,
                                               const float* __restrict__ cb,
                                               const float* __restrict__ db1,
                                               const float* __restrict__ tb1,
                                               float* __restrict__ hbuf,
                                               float* __restrict__ U,
                                               float* __restrict__ Vv,
                                               float* __restrict__ t1t) {
    size_t woff; int ldw, koff, act; const float* bias; float* C;
    const int z = blockIdx.z;
    if (z == 0)      { woff = OFF_CW;  ldw = 256; koff = 0;   bias = cb;      act = 0; C = hbuf; }
    else if (z == 1) { woff = OFF_DW1; ldw = 512; koff = 0;   bias = db1;     act = 0; C = U; }
    else if (z == 2) { woff = OFF_DW1; ldw = 512; koff = 256; bias = nullptr; act = 0; C = Vv; }
    else             { woff = OFF_TW1; ldw = 256; koff = 0;   bias = tb1;     act = 2; C = t1t; }

    __shared__ ushort Al[2][2048];
    __shared__ ushort Wl[2][2048];
    const int t = threadIdx.x;
    const int bm = blockIdx.y * 64, bn = blockIdx.x * 64;
    const int lane = t & 63, wv = t >> 6;
    const int lo = lane & 15, hi = lane >> 4;

    const ushort* aptr = A + (size_t)(bm + lane) * 256 + wv * 8;
    const ushort* wptr = Wb + woff + (size_t)(bn + lane) * ldw + koff + wv * 8;

    f32x4 acc0 = {0.f, 0.f, 0.f, 0.f}, acc1 = acc0, acc2 = acc0, acc3 = acc0;
    uint4 a = *(const uint4*)aptr;
    uint4 w = *(const uint4*)wptr;
    for (int s = 0; s < 8; ++s) {
        const int buf = s & 1;
        *(uint4*)&Al[buf][t * 8] = a;
        *(uint4*)&Wl[buf][t * 8] = w;
        __syncthreads();
        if (s < 7) {
            a = *(const uint4*)(aptr + (s + 1) * 32);
            w = *(const uint4*)(wptr + (s + 1) * 32);
        }
        bf16x8 af = *(bf16x8*)&Al[buf][(hi * 64 + wv * 16 + lo) * 8];
        bf16x8 b0 = *(bf16x8*)&Wl[buf][(hi * 64 + 0 + lo) * 8];
        bf16x8 b1 = *(bf16x8*)&Wl[buf][(hi * 64 + 16 + lo) * 8];
        bf16x8 b2 = *(bf16x8*)&Wl[buf][(hi * 64 + 32 + lo) * 8];
        bf16x8 b3 = *(bf16x8*)&Wl[buf][(hi * 64 + 48 + lo) * 8];
        acc0 = __builtin_amdgcn_mfma_f32_16x16x32_bf16(af, b0, acc0, 0, 0, 0);
        acc1 = __builtin_amdgcn_mfma_f32_16x16x32_bf16(af, b1, acc1, 0, 0, 0);
        acc2 = __builtin_amdgcn_mfma_f32_16x16x32_bf16(af, b2, acc2, 0, 0, 0);
        acc3 = __builtin_amdgcn_mfma_f32_16x16x32_bf16(af, b3, acc3, 0, 0, 0);
    }

    float bv0 = bias ? bias[bn + 0 + lo] : 0.0f;
    float bv1 = bias ? bias[bn + 16 + lo] : 0.0f;
    float bv2 = bias ? bias[bn + 32 + lo] : 0.0f;
    float bv3 = bias ? bias[bn + 48 + lo] : 0.0f;
#pragma unroll
    for (int r = 0; r < 4; ++r) {
        size_t rw = (size_t)(bm + wv * 16 + hi * 4 + r) * 256 + bn;
        float v0 = acc0[r] + bv0, v1 = acc1[r] + bv1, v2 = acc2[r] + bv2, v3 = acc3[r] + bv3;
        if (act == 2) { v0 = gelu_f(v0); v1 = gelu_f(v1); v2 = gelu_f(v2); v3 = gelu_f(v3); }
        C[rw + 0 + lo] = v0;
        C[rw + 16 + lo] = v1;
        C[rw + 32 + lo] = v2;
        C[rw + 48 + lo] = v3;
    }
}

// ---------------- attention: K staged in bf16 LDS (coalesced), wave per (head, query) ----------------
__global__ __launch_bounds__(256) void attn_k(const float* __restrict__ qkv,
                                              ushort* __restrict__ ob) {
    __shared__ ushort kl[512 * 34];
    __shared__ float sc[4][512];
    int t = threadIdx.x;
    int h = blockIdx.y;

    {
        int row = t >> 2;
        const int q8 = (t & 3) * 8;
#pragma unroll
        for (int it = 0; it < 8; ++it, row += 64) {
            const float* src = qkv + (size_t)row * 768 + 256 + h * 32 + q8;
            float4 a = *(const float4*)src;
            float4 b = *(const float4*)(src + 4);
            *(uint4*)&kl[row * 34 + q8] = pack_bf8(a, b);
        }
    }
    __syncthreads();

    int w = t >> 6, lane = t & 63;
    int q = blockIdx.x * 4 + w;
    const float* qptr = qkv + (size_t)q * 768 + h * 32;
    const float* vbase = qkv + 512 + h * 32;
    float qv[32];
#pragma unroll
    for (int d = 0; d < 32; d += 4) {
        float4 f = *(const float4*)(qptr + d);
        qv[d] = f.x; qv[d + 1] = f.y; qv[d + 2] = f.z; qv[d + 3] = f.w;
    }
    float mx = -1e30f;
    for (int k = lane; k < 512; k += 64) {
        const ushort* kp = &kl[k * 34];
        uint4 r0 = *(const uint4*)kp;
        uint4 r1 = *(const uint4*)(kp + 8);
        uint4 r2 = *(const uint4*)(kp + 16);
        uint4 r3 = *(const uint4*)(kp + 24);
        float s = 0.0f;
        s = fmaf(qv[0],  blo(r0.x), s); s = fmaf(qv[1],  bhi(r0.x), s);
        s = fmaf(qv[2],  blo(r0.y), s); s = fmaf(qv[3],  bhi(r0.y), s);
        s = fmaf(qv[4],  blo(r0.z), s); s = fmaf(qv[5],  bhi(r0.z), s);
        s = fmaf(qv[6],  blo(r0.w), s); s = fmaf(qv[7],  bhi(r0.w), s);
        s = fmaf(qv[8],  blo(r1.x), s); s = fmaf(qv[9],  bhi(r1.x), s);
        s = fmaf(qv[10], blo(r1.y), s); s = fmaf(qv[11], bhi(r1.y), s);
        s = fmaf(qv[12], blo(r1.z), s); s = fmaf(qv[13], bhi(r1.z), s);
        s = fmaf(qv[14], blo(r1.w), s); s = fmaf(qv[15], bhi(r1.w), s);
        s = fmaf(qv[16], blo(r2.x), s); s = fmaf(qv[17], bhi(r2.x), s);
        s = fmaf(qv[18], blo(r2.y), s); s = fmaf(qv[19], bhi(r2.y), s);
        s = fmaf(qv[20], blo(r2.z), s); s = fmaf(qv[21], bhi(r2.z), s);
        s = fmaf(qv[22], blo(r2.w), s); s = fmaf(qv[23], bhi(r2.w), s);
        s = fmaf(qv[24], blo(r3.x), s); s = fmaf(qv[25], bhi(r3.x), s);
        s = fmaf(qv[26], blo(r3.y), s); s = fmaf(qv[27], bhi(r3.y), s);
        s = fmaf(qv[28], blo(r3.z), s); s = fmaf(qv[29], bhi(r3.z), s);
        s = fmaf(qv[30], blo(r3.w), s); s = fmaf(qv[31], bhi(r3.w), s);
        s *= 0.17677669529663687f;
        sc[w][k] = s;
        mx = fmaxf(mx, s);
    }
    mx = wave_max(mx);
    float sum = 0.0f;
    for (int k = lane; k < 512; k += 64) {
        float e = expf(sc[w][k] - mx);
        sc[w][k] = e;
        sum += e;
    }
    sum = wave_sum(sum);
    float inv = 1.0f / sum;
    __syncthreads();
    int d = lane & 31, half = lane >> 5;
    const float* vp = vbase + d;
    const int kb = half * 256;
    float a0 = 0.f, a1 = 0.f, a2 = 0.f, a3 = 0.f;
    float a4 = 0.f, a5 = 0.f, a6 = 0.f, a7 = 0.f;
    for (int k = kb; k < kb + 256; k += 8) {
        float4 p0 = *(const float4*)&sc[w][k];
        float4 p1 = *(const float4*)&sc[w][k + 4];
        a0 = fmaf(p0.x, vp[(size_t)(k + 0) * 768], a0);
        a1 = fmaf(p0.y, vp[(size_t)(k + 1) * 768], a1);
        a2 = fmaf(p0.z, vp[(size_t)(k + 2) * 768], a2);
        a3 = fmaf(p0.w, vp[(size_t)(k + 3) * 768], a3);
        a4 = fmaf(p1.x, vp[(size_t)(k + 4) * 768], a4);
        a5 = fmaf(p1.y, vp[(size_t)(k + 5) * 768], a5);
        a6 = fmaf(p1.z, vp[(size_t)(k + 6) * 768], a6);
        a7 = fmaf(p1.w, vp[(size_t)(k + 7) * 768], a7);
    }
    float accv = ((a0 + a1) + (a2 + a3)) + ((a4 + a5) + (a6 + a7));
    accv += __shfl_down(accv, 32);
    if (lane < 32) ob[(size_t)q * 256 + h * 32 + d] = f2bfu(accv * inv);
}

// ---------------- alpha head ----------------
__global__ void alpha_k(const float* __restrict__ t1, const float* __restrict__ aW2,
                        const float* __restrict__ ab2, float* __restrict__ alphaf,
                        float* __restrict__ out_alpha) {
    int t = threadIdx.x, w = t >> 6, lane = t & 63;
    int n = blockIdx.x * 4 + w;
    const float* r = t1 + (size_t)n * 256;
    float s = 0.0f;
    for (int d = lane; d < 256; d += 64) s = fmaf(r[d], aW2[d], s);
    s = wave_sum(s);
    if (lane == 0) {
        float z = s + ab2[0];
        float a = 1.0f / (1.0f + expf(-z));
        float al = 1.2f + 2.3f * a;
        alphaf[n] = al;
        out_alpha[n] = al;
    }
}

// ---------------- CSOC kernel attention ----------------
__global__ void csock_k(const float* __restrict__ x, const float* __restrict__ alphaf,
                        float* __restrict__ latent, float* __restrict__ out_latent,
                        ushort* __restrict__ latentb) {
    int i = blockIdx.x, t = threadIdx.x;
    __shared__ float wgt[512];
    __shared__ float red[4];
    float ai = alphaf[i];
    float lsum = 0.0f;
    for (int j = t; j < 512; j += 256) {
        float r = fabsf((float)(i - j)) + 1e-4f;
        float ap = 0.5f * (ai + alphaf[j]);
        float wv = powf(r, -ap) * expf(-r * 0.1f);
        wgt[j] = wv;
        lsum += wv;
    }
    float s = wave_sum(lsum);
    if ((t & 63) == 0) red[t >> 6] = s;
    __syncthreads();
    float S = red[0] + red[1] + red[2] + red[3] + 1e-8f;
    float acc = 0.0f;
    for (int j = 0; j < 512; ++j) acc = fmaf(wgt[j], x[(size_t)j * 256 + t], acc);
    float res = acc / S;
    latent[(size_t)i * 256 + t] = res;
    out_latent[(size_t)i * 256 + t] = res;
    latentb[(size_t)i * 256 + t] = f2bfu(res);
}

// ---------------- merged finals: contact (512 blk) + torsion (128 blk) + diff (6 blk) ----------------
__global__ __launch_bounds__(256) void finals_k(const float* __restrict__ h,
                                                const float* __restrict__ t1t,
                                                const float* __restrict__ latentf,
                                                const float* __restrict__ tW2,
                                                const float* __restrict__ tb2,
                                                const float* __restrict__ pW,
                                                const float* __restrict__ pb,
                                                const float* __restrict__ noise,
                                                float* __restrict__ out_contact,
                                                float* __restrict__ phi,
                                                float* __restrict__ psi,
                                                float* __restrict__ outc) {
    const int blk = blockIdx.x;
    const int t = threadIdx.x;
    if (blk < 512) {
        int i = blk;
        __shared__ float hi_s[256];
        hi_s[t] = h[(size_t)i * 256 + t];
        __syncthreads();
        for (int j = t; j < 512; j += 256) {
            const float* hj = h + (size_t)j * 256;
            float s = 0.0f;
#pragma unroll 4
            for (int d = 0; d < 256; d += 4) {
                float4 a = *(const float4*)&hi_s[d];
                float4 b = *(const float4*)&hj[d];
                s = fmaf(a.x, b.x, s); s = fmaf(a.y, b.y, s);
                s = fmaf(a.z, b.z, s); s = fmaf(a.w, b.w, s);
            }
            out_contact[(size_t)i * 512 + j] = 1.0f / (1.0f + expf(-s));
        }
    } else if (blk < 640) {
        int w = t >> 6, lane = t & 63;
        int n = (blk - 512) * 4 + w;
        const float* r = t1t + (size_t)n * 256;
        float s0 = 0.0f, s1 = 0.0f;
        for (int d = lane; d < 256; d += 64) {
            float v = r[d];
            s0 = fmaf(v, tW2[d], s0);
            s1 = fmaf(v, tW2[256 + d], s1);
        }
        s0 = wave_sum(s0);
        s1 = wave_sum(s1);
        if (lane == 0) {
            phi[n] = tanhf(s0 + tb2[0]) * 3.14159265358979323846f;
            psi[n] = tanhf(s1 + tb2[1]) * 3.14159265358979323846f;
        }
    } else {
        int idx = (blk - 640) * 256 + t;
        if (idx >= 512 * 3) return;
        int n = idx / 3, a = idx % 3;
        const float* r = latentf + (size_t)n * 256;
        float s = pb[a];
        for (int d = 0; d < 256; ++d) s = fmaf(r[d], pW[(size_t)a * 256 + d], s);
        float c = noise[idx];
#pragma unroll
        for (int st = 9; st >= 0; --st) {
            float at = (float)(st + 1) * 0.1f;
            c = at * c + (1.0f - at) * s;
        }
        outc[idx] = c;
    }
}

// ---------------- distogram v5 + fast gelu ----------------
__global__ __launch_bounds__(256) void disto_k(const float* __restrict__ U,
                                               const float* __restrict__ V,
                                               const float* __restrict__ dW2,
                                               const float* __restrict__ db2,
                                               float* __restrict__ out) {
    __shared__ short w2l[32 * 64 * 8];
    const int t = threadIdx.x;
    const int i = blockIdx.x;

    {
        const int brow = t >> 2, dq = t & 3;
#pragma unroll
        for (int c = 0; c < 8; ++c) {
            int dblk = dq * 8 + c;
            int d0 = dblk * 8;
            float4 w0 = *(const float4*)&dW2[(size_t)brow * 256 + d0];
            float4 w1 = *(const float4*)&dW2[(size_t)brow * 256 + d0 + 4];
            *(uint4*)&w2l[(dblk * 64 + brow) * 8] = pack_bf8(w0, w1);
        }
    }
    __syncthreads();

    const int wv = t >> 6, lane = t & 63;
    const int lo = lane & 15, hi = lane >> 4;

    float4 uf0[8], uf1[8];
#pragma unroll
    for (int kk = 0; kk < 8; ++kk) {
        uf0[kk] = *(const float4*)&U[(size_t)i * 256 + kk * 32 + hi * 8];
        uf1[kk] = *(const float4*)&U[(size_t)i * 256 + kk * 32 + hi * 8 + 4];
    }
    float dbv[4];
#pragma unroll
    for (int nt = 0; nt < 4; ++nt) dbv[nt] = db2[nt * 16 + lo];

    for (int p = 0; p < 8; ++p) {
        const int j = p * 64 + wv * 16 + lo;
        const float* vrow = V + (size_t)j * 256;
        f32x4 acc0 = {0.f, 0.f, 0.f, 0.f}, acc1 = acc0, acc2 = acc0, acc3 = acc0;
#pragma unroll
        for (int kk = 0; kk < 8; ++kk) {
            float4 v0 = *(const float4*)&vrow[kk * 32 + hi * 8];
            float4 v1 = *(const float4*)&vrow[kk * 32 + hi * 8 + 4];
            float4 h0, h1;
            h0.x = gelu_fast(uf0[kk].x + v0.x); h0.y = gelu_fast(uf0[kk].y + v0.y);
            h0.z = gelu_fast(uf0[kk].z + v0.z); h0.w = gelu_fast(uf0[kk].w + v0.w);
            h1.x = gelu_fast(uf1[kk].x + v1.x); h1.y = gelu_fast(uf1[kk].y + v1.y);
            h1.z = gelu_fast(uf1[kk].z + v1.z); h1.w = gelu_fast(uf1[kk].w + v1.w);
            uint4 ap = pack_bf8(h0, h1);
            bf16x8 a = *(bf16x8*)&ap;
            int db = kk * 4 + hi;
            bf16x8 b0 = *(bf16x8*)&w2l[(db * 64 + 0 + lo) * 8];
            bf16x8 b1 = *(bf16x8*)&w2l[(db * 64 + 16 + lo) * 8];
            bf16x8 b2 = *(bf16x8*)&w2l[(db * 64 + 32 + lo) * 8];
            bf16x8 b3 = *(bf16x8*)&w2l[(db * 64 + 48 + lo) * 8];
            acc0 = __builtin_amdgcn_mfma_f32_16x16x32_bf16(a, b0, acc0, 0, 0, 0);
            acc1 = __builtin_amdgcn_mfma_f32_16x16x32_bf16(a, b1, acc1, 0, 0, 0);
            acc2 = __builtin_amdgcn_mfma_f32_16x16x32_bf16(a, b2, acc2, 0, 0, 0);
            acc3 = __builtin_amdgcn_mfma_f32_16x16x32_bf16(a, b3, acc3, 0, 0, 0);
        }
#pragma unroll
        for (int r = 0; r < 4; ++r) {
            size_t jg = (size_t)i * 512 + p * 64 + wv * 16 + hi * 4 + r;
            out[jg * 64 + 0 + lo] = acc0[r] + dbv[0];
            out[jg * 64 + 16 + lo] = acc1[r] + dbv[1];
            out[jg * 64 + 32 + lo] = acc2[r] + dbv[2];
            out[jg * 64 + 48 + lo] = acc3[r] + dbv[3];
        }
    }
}

extern "C" void kernel_launch(void* const* d_in, const int* in_sizes, int n_in,
                              void* d_out, int out_size, void* d_ws, size_t ws_size,
                              hipStream_t stream) {
    const int* tokens  = (const int*)d_in[0];
    const float* noise = (const float*)d_in[1];
    const float* emb   = (const float*)d_in[2];
    const float* Wqkv  = (const float*)d_in[3];
    const float* bqkv  = (const float*)d_in[4];
    const float* Wo    = (const float*)d_in[5];
    const float* bo    = (const float*)d_in[6];
    const float* ln1_g = (const float*)d_in[7];
    const float* ln1_b = (const float*)d_in[8];
    const float* W1    = (const float*)d_in[9];
    const float* b1    = (const float*)d_in[10];
    const float* W2    = (const float*)d_in[11];
    const float* b2    = (const float*)d_in[12];
    const float* ln2_g = (const float*)d_in[13];
    const float* ln2_b = (const float*)d_in[14];
    const float* aW1   = (const float*)d_in[15];
    const float* ab1   = (const float*)d_in[16];
    const float* aW2   = (const float*)d_in[17];
    const float* ab2   = (const float*)d_in[18];
    const float* cW    = (const float*)d_in[19];
    const float* cb    = (const float*)d_in[20];
    const float* dW1   = (const float*)d_in[21];
    const float* db1   = (const float*)d_in[22];
    const float* dW2   = (const float*)d_in[23];
    const float* db2   = (const float*)d_in[24];
    const float* tW1   = (const float*)d_in[25];
    const float* tb1   = (const float*)d_in[26];
    const float* tW2   = (const float*)d_in[27];
    const float* tb2   = (const float*)d_in[28];
    const float* pW    = (const float*)d_in[29];
    const float* pb    = (const float*)d_in[30];

    // output layout (FLOAT32, concatenated in return order)
    float* out         = (float*)d_out;
    float* out_latent  = out;               // 131072
    float* out_alpha   = out + 131072;      // 512
    float* out_contact = out + 131584;      // 262144
    float* out_disto   = out + 393728;      // 16777216
    float* out_phi     = out + 17170944;    // 512
    float* out_psi     = out + 17171456;    // 512
    float* out_c       = out + 17171968;    // 1536

    // transient scratch inside out_disto; disto_k runs LAST.
    float* scratch = out_disto;
    float* x    = scratch;             // 131072 f32
    float* qkv  = scratch + 131072;    // 393216 f32
    float* t1t  = scratch + 655360;    // 131072 f32 (torsion t1)
    float* y    = scratch + 1179648;   // 131072 f32
    float* hbuf = scratch + 1310720;   // 131072 f32
    float* t1a  = scratch + 1441792;   // 131072 f32 (alpha t1)
    ushort* wb      = (ushort*)(scratch + 2000000);  // 3473408 bf16
    ushort* xb      = (ushort*)(scratch + 3740000);  // 131072 bf16
    ushort* ob      = (ushort*)(scratch + 3810000);  // 131072 bf16
    ushort* ffhb    = (ushort*)(scratch + 3880000);  // 524288 bf16
    ushort* latentb = (ushort*)(scratch + 4150000);  // 131072 bf16
    float* yp   = scratch + 4300000;   // 524288 f32 (4 split-K slices)
    float* xn   = scratch + 4900000;   // 131072 f32 (post-LN1 residual)

    // persistent across disto_k: keep in d_ws
    float* latentf = (float*)d_ws;      // 131072
    float* U       = latentf + 131072;  // 131072
    float* Vv      = U + 131072;        // 131072
    float* alphaf  = Vv + 131072;       // 512

    convw_k<<<1696, 256, 0, stream>>>(Wqkv, Wo, W1, W2, aW1, cW, dW1, tW1, wb);
    embed_k<<<512, 256, 0, stream>>>(tokens, emb, x, xb);

    for (int l = 0; l < 4; ++l) {
        gemm_bf<0, 0><<<dim3(12, 8), 256, 0, stream>>>(xb, wb, bqkv, qkv, nullptr,
                                                       768, 256, 256, 256, 0,
                                                       OFF_QKV + (size_t)l * 196608, (size_t)l * 768);
        attn_k<<<dim3(128, 8), 256, 0, stream>>>(qkv, ob);
        gemm_bf<0, 0><<<dim3(4, 8), 256, 0, stream>>>(ob, wb, bo, y, nullptr,
                                                      256, 256, 256, 256, 0,
                                                      OFF_WO + (size_t)l * 65536, (size_t)l * 256);
        // fused LN1 + FFN1 (+ReLU): writes ffhb and xn (post-LN1, for ln2 residual)
        ffn1_ln_k<<<dim3(16, 8), 256, 0, stream>>>(x, y, ln1_g, ln1_b, wb, b1, xn, ffhb,
                                                   (size_t)l * 256,
                                                   OFF_W1 + (size_t)l * 262144,
                                                   (size_t)l * 1024);
        ffn2_splitk<<<dim3(4, 8, 4), 256, 0, stream>>>(ffhb, wb, yp,
                                                       OFF_W2 + (size_t)l * 262144);
        ln_res4_k<<<512, 256, 0, stream>>>(xn, yp, b2, (size_t)l * 256,
                                           ln2_g, ln2_b, (size_t)l * 256, x, xb);
    }

    // alpha head: t1a = gelu(x.aW1^T + ab1) via MFMA
    gemm_bf<2, 0><<<dim3(4, 8), 256, 0, stream>>>(xb, wb, ab1, t1a, nullptr,
                                                  256, 256, 256, 256, 0, OFF_AW1, 0);
    alpha_k<<<128, 256, 0, stream>>>(t1a, aW2, ab2, alphaf, out_alpha);

    // CSOC kernel attention -> latent (f32 + bf16)
    csock_k<<<512, 256, 0, stream>>>(x, alphaf, latentf, out_latent, latentb);

    // batched head GEMMs: contact-h, U, V, torsion-t1
    heads_k<<<dim3(4, 8, 4), 256, 0, stream>>>(latentb, wb, cb, db1, tb1,
                                               hbuf, U, Vv, t1t);

    // merged contact + torsion + diffusion
    finals_k<<<646, 256, 0, stream>>>(hbuf, t1t, latentf, tW2, tb2, pW, pb, noise,
                                      out_contact, out_phi, out_psi, out_c);

    // distogram LAST: overwrites the scratch region with the real output
    disto_k<<<512, 256, 0, stream>>>(U, Vv, dW2, db2, out_disto);
}

// Round 19
// 422.329 us; speedup vs baseline: 1.2254x; 1.2254x over previous
//
#include <hip/hip_runtime.h>
#include <hip/hip_bf16.h>

typedef __attribute__((ext_vector_type(8))) short bf16x8;
typedef __attribute__((ext_vector_type(4))) float f32x4;
typedef unsigned short ushort;

// bf16 element offsets inside the converted-weight buffer wb
#define OFF_QKV 0
#define OFF_WO  786432
#define OFF_W1  1048576
#define OFF_W2  2097152
#define OFF_AW1 3145728
#define OFF_CW  3211264
#define OFF_DW1 3276800
#define OFF_TW1 3407872
#define WB_TOTAL 3473408

__device__ inline float gelu_f(float x) {
    return 0.5f * x * (1.0f + erff(x * 0.70710678118654752f));
}

__device__ inline ushort f2bfu(float x) {
    __hip_bfloat16 b = __float2bfloat16(x);
    return *reinterpret_cast<ushort*>(&b);
}

__device__ inline float blo(unsigned u) { return __uint_as_float(u << 16); }
__device__ inline float bhi(unsigned u) { return __uint_as_float(u & 0xffff0000u); }

__device__ inline uint4 pack_bf8(float4 a, float4 b) {
    uint4 p;
    p.x = f2bfu(a.x) | ((unsigned)f2bfu(a.y) << 16);
    p.y = f2bfu(a.z) | ((unsigned)f2bfu(a.w) << 16);
    p.z = f2bfu(b.x) | ((unsigned)f2bfu(b.y) << 16);
    p.w = f2bfu(b.z) | ((unsigned)f2bfu(b.w) << 16);
    return p;
}

__device__ inline float wave_sum(float v) {
#pragma unroll
    for (int o = 32; o > 0; o >>= 1) v += __shfl_xor(v, o);
    return v;
}
__device__ inline float wave_max(float v) {
#pragma unroll
    for (int o = 32; o > 0; o >>= 1) v = fmaxf(v, __shfl_xor(v, o));
    return v;
}

// ---------------- merged prep: weight conversion (blk<1696) + embedding (blk>=1696) ----------------
__global__ void prep_k(const float* __restrict__ Wqkv, const float* __restrict__ Wo,
                       const float* __restrict__ W1, const float* __restrict__ W2,
                       const float* __restrict__ aW1, const float* __restrict__ cW,
                       const float* __restrict__ dW1, const float* __restrict__ tW1,
                       ushort* __restrict__ dst,
                       const int* __restrict__ tokens, const float* __restrict__ emb,
                       float* __restrict__ x, ushort* __restrict__ xb) {
    const int blk = blockIdx.x;
    const int t = threadIdx.x;
    if (blk < 1696) {
        size_t i = ((size_t)blk * 256 + t) * 8;
        if (i >= WB_TOTAL) return;
        const float* src;
        size_t off;
        if (i < OFF_WO)        { src = Wqkv; off = i; }
        else if (i < OFF_W1)   { src = Wo;   off = i - OFF_WO; }
        else if (i < OFF_W2)   { src = W1;   off = i - OFF_W1; }
        else if (i < OFF_AW1)  { src = W2;   off = i - OFF_W2; }
        else if (i < OFF_CW)   { src = aW1;  off = i - OFF_AW1; }
        else if (i < OFF_DW1)  { src = cW;   off = i - OFF_CW; }
        else if (i < OFF_TW1)  { src = dW1;  off = i - OFF_DW1; }
        else                   { src = tW1;  off = i - OFF_TW1; }
        float4 f0 = *(const float4*)&src[off];
        float4 f1 = *(const float4*)&src[off + 4];
        *(uint4*)&dst[i] = pack_bf8(f0, f1);
    } else {
        int n = blk - 1696;
        float e = emb[(size_t)tokens[n] * 256 + t];
        int k = t >> 1;
        float div = expf((float)(2 * k) * (-9.210340371976184f / 256.0f));
        float arg = (float)n * div;
        float v = e + ((t & 1) ? cosf(arg) : sinf(arg));
        x[(size_t)n * 256 + t] = v;
        xb[(size_t)n * 256 + t] = f2bfu(v);
    }
}

// ---------------- MFMA GEMM, bf16 in / {f32 or bf16} out (64x64 tile) ----------------
template <int ACT, int OBF>
__global__ __launch_bounds__(256) void gemm_bf(const ushort* __restrict__ A,
                                               const ushort* __restrict__ Wb,
                                               const float* __restrict__ bias,
                                               float* __restrict__ C,
                                               ushort* __restrict__ Cb,
                                               int Nn, int K, int lda, int ldw, int koff,
                                               size_t woff, size_t boff) {
    __shared__ ushort Al[2][2048];
    __shared__ ushort Wl[2][2048];
    const int t = threadIdx.x;
    const int bm = blockIdx.y * 64, bn = blockIdx.x * 64;
    const int lane = t & 63, wv = t >> 6;
    const int lo = lane & 15, hi = lane >> 4;

    const ushort* aptr = A + (size_t)(bm + lane) * lda + wv * 8;
    const ushort* wptr = Wb + woff + (size_t)(bn + lane) * ldw + koff + wv * 8;

    f32x4 acc0 = {0.f, 0.f, 0.f, 0.f}, acc1 = acc0, acc2 = acc0, acc3 = acc0;
    uint4 a = *(const uint4*)aptr;
    uint4 w = *(const uint4*)wptr;
    const int nsteps = K >> 5;
    for (int s = 0; s < nsteps; ++s) {
        const int buf = s & 1;
        *(uint4*)&Al[buf][t * 8] = a;
        *(uint4*)&Wl[buf][t * 8] = w;
        __syncthreads();
        if (s + 1 < nsteps) {
            a = *(const uint4*)(aptr + (s + 1) * 32);
            w = *(const uint4*)(wptr + (s + 1) * 32);
        }
        bf16x8 af = *(bf16x8*)&Al[buf][(hi * 64 + wv * 16 + lo) * 8];
        bf16x8 b0 = *(bf16x8*)&Wl[buf][(hi * 64 + 0 + lo) * 8];
        bf16x8 b1 = *(bf16x8*)&Wl[buf][(hi * 64 + 16 + lo) * 8];
        bf16x8 b2 = *(bf16x8*)&Wl[buf][(hi * 64 + 32 + lo) * 8];
        bf16x8 b3 = *(bf16x8*)&Wl[buf][(hi * 64 + 48 + lo) * 8];
        acc0 = __builtin_amdgcn_mfma_f32_16x16x32_bf16(af, b0, acc0, 0, 0, 0);
        acc1 = __builtin_amdgcn_mfma_f32_16x16x32_bf16(af, b1, acc1, 0, 0, 0);
        acc2 = __builtin_amdgcn_mfma_f32_16x16x32_bf16(af, b2, acc2, 0, 0, 0);
        acc3 = __builtin_amdgcn_mfma_f32_16x16x32_bf16(af, b3, acc3, 0, 0, 0);
    }

    float bv0 = bias ? bias[boff + bn + 0 + lo] : 0.0f;
    float bv1 = bias ? bias[boff + bn + 16 + lo] : 0.0f;
    float bv2 = bias ? bias[boff + bn + 32 + lo] : 0.0f;
    float bv3 = bias ? bias[boff + bn + 48 + lo] : 0.0f;
#pragma unroll
    for (int r = 0; r < 4; ++r) {
        size_t rw = (size_t)(bm + wv * 16 + hi * 4 + r) * Nn + bn;
        float v0 = acc0[r] + bv0, v1 = acc1[r] + bv1, v2 = acc2[r] + bv2, v3 = acc3[r] + bv3;
        if (ACT == 1) {
            v0 = fmaxf(v0, 0.f); v1 = fmaxf(v1, 0.f); v2 = fmaxf(v2, 0.f); v3 = fmaxf(v3, 0.f);
        }
        if (ACT == 2) {
            v0 = gelu_f(v0); v1 = gelu_f(v1); v2 = gelu_f(v2); v3 = gelu_f(v3);
        }
        if (OBF) {
            Cb[rw + 0 + lo] = f2bfu(v0);
            Cb[rw + 16 + lo] = f2bfu(v1);
            Cb[rw + 32 + lo] = f2bfu(v2);
            Cb[rw + 48 + lo] = f2bfu(v3);
        } else {
            C[rw + 0 + lo] = v0;
            C[rw + 16 + lo] = v1;
            C[rw + 32 + lo] = v2;
            C[rw + 48 + lo] = v3;
        }
    }
}

// ---------------- FFN2 split-K: grid (4, 8, 4); slice z covers K in [z*256, z*256+256) ----------------
__global__ __launch_bounds__(256) void ffn2_splitk(const ushort* __restrict__ A,
                                                   const ushort* __restrict__ Wb,
                                                   float* __restrict__ yp,
                                                   size_t woff) {
    __shared__ ushort Al[2][2048];
    __shared__ ushort Wl[2][2048];
    const int t = threadIdx.x;
    const int bm = blockIdx.y * 64, bn = blockIdx.x * 64;
    const int ks = blockIdx.z;
    const int lane = t & 63, wv = t >> 6;
    const int lo = lane & 15, hi = lane >> 4;

    const ushort* aptr = A + (size_t)(bm + lane) * 1024 + ks * 256 + wv * 8;
    const ushort* wptr = Wb + woff + (size_t)(bn + lane) * 1024 + ks * 256 + wv * 8;

    f32x4 acc0 = {0.f, 0.f, 0.f, 0.f}, acc1 = acc0, acc2 = acc0, acc3 = acc0;
    uint4 a = *(const uint4*)aptr;
    uint4 w = *(const uint4*)wptr;
    for (int s = 0; s < 8; ++s) {
        const int buf = s & 1;
        *(uint4*)&Al[buf][t * 8] = a;
        *(uint4*)&Wl[buf][t * 8] = w;
        __syncthreads();
        if (s < 7) {
            a = *(const uint4*)(aptr + (s + 1) * 32);
            w = *(const uint4*)(wptr + (s + 1) * 32);
        }
        bf16x8 af = *(bf16x8*)&Al[buf][(hi * 64 + wv * 16 + lo) * 8];
        bf16x8 b0 = *(bf16x8*)&Wl[buf][(hi * 64 + 0 + lo) * 8];
        bf16x8 b1 = *(bf16x8*)&Wl[buf][(hi * 64 + 16 + lo) * 8];
        bf16x8 b2 = *(bf16x8*)&Wl[buf][(hi * 64 + 32 + lo) * 8];
        bf16x8 b3 = *(bf16x8*)&Wl[buf][(hi * 64 + 48 + lo) * 8];
        acc0 = __builtin_amdgcn_mfma_f32_16x16x32_bf16(af, b0, acc0, 0, 0, 0);
        acc1 = __builtin_amdgcn_mfma_f32_16x16x32_bf16(af, b1, acc1, 0, 0, 0);
        acc2 = __builtin_amdgcn_mfma_f32_16x16x32_bf16(af, b2, acc2, 0, 0, 0);
        acc3 = __builtin_amdgcn_mfma_f32_16x16x32_bf16(af, b3, acc3, 0, 0, 0);
    }

    float* yo = yp + (size_t)ks * 131072;
#pragma unroll
    for (int r = 0; r < 4; ++r) {
        size_t rw = (size_t)(bm + wv * 16 + hi * 4 + r) * 256 + bn;
        yo[rw + 0 + lo] = acc0[r];
        yo[rw + 16 + lo] = acc1[r];
        yo[rw + 32 + lo] = acc2[r];
        yo[rw + 48 + lo] = acc3[r];
    }
}

// ---------------- residual + LayerNorm over 4 split-K slices + bias ----------------
__global__ void ln_res4_k(float* __restrict__ x, const float* __restrict__ yp,
                          const float* __restrict__ b2, size_t b2off,
                          const float* __restrict__ g, const float* __restrict__ b,
                          size_t goff, ushort* __restrict__ xb) {
    int row = blockIdx.x, t = threadIdx.x;
    __shared__ float red[8];
    size_t idx = (size_t)row * 256 + t;
    float v = x[idx] + ((yp[idx] + yp[idx + 131072]) + (yp[idx + 262144] + yp[idx + 393216]))
            + b2[b2off + t];
    float s = wave_sum(v);
    if ((t & 63) == 0) red[t >> 6] = s;
    __syncthreads();
    float mean = (red[0] + red[1] + red[2] + red[3]) * (1.0f / 256.0f);
    float d = v - mean;
    float s2 = wave_sum(d * d);
    if ((t & 63) == 0) red[4 + (t >> 6)] = s2;
    __syncthreads();
    float var = (red[4] + red[5] + red[6] + red[7]) * (1.0f / 256.0f);
    float res = d * rsqrtf(var + 1e-5f) * g[goff + t] + b[goff + t];
    x[idx] = res;
    xb[idx] = f2bfu(res);
}

// ---------------- batched head GEMMs: z = {contact-h, disto-U, disto-V, torsion-t1} ----------------
__global__ __launch_bounds__(256) void heads_k(const ushort* __restrict__ A,
                                               const ushort* __restrict__ Wb,
                                               const float* __restrict__ cb,
                                               const float* __restrict__ db1,
                                               const float* __restrict__ tb1,
                                               float* __restrict__ hbuf,
                                               float* __restrict__ U,
                                               float* __restrict__ Vv,
                                               float* __restrict__ t1t) {
    size_t woff; int ldw, koff, act; const float* bias; float* C;
    const int z = blockIdx.z;
    if (z == 0)      { woff = OFF_CW;  ldw = 256; koff = 0;   bias = cb;      act = 0; C = hbuf; }
    else if (z == 1) { woff = OFF_DW1; ldw = 512; koff = 0;   bias = db1;     act = 0; C = U; }
    else if (z == 2) { woff = OFF_DW1; ldw = 512; koff = 256; bias = nullptr; act = 0; C = Vv; }
    else             { woff = OFF_TW1; ldw = 256; koff = 0;   bias = tb1;     act = 2; C = t1t; }

    __shared__ ushort Al[2][2048];
    __shared__ ushort Wl[2][2048];
    const int t = threadIdx.x;
    const int bm = blockIdx.y * 64, bn = blockIdx.x * 64;
    const int lane = t & 63, wv = t >> 6;
    const int lo = lane & 15, hi = lane >> 4;

    const ushort* aptr = A + (size_t)(bm + lane) * 256 + wv * 8;
    const ushort* wptr = Wb + woff + (size_t)(bn + lane) * ldw + koff + wv * 8;

    f32x4 acc0 = {0.f, 0.f, 0.f, 0.f}, acc1 = acc0, acc2 = acc0, acc3 = acc0;
    uint4 a = *(const uint4*)aptr;
    uint4 w = *(const uint4*)wptr;
    for (int s = 0; s < 8; ++s) {
        const int buf = s & 1;
        *(uint4*)&Al[buf][t * 8] = a;
        *(uint4*)&Wl[buf][t * 8] = w;
        __syncthreads();
        if (s < 7) {
            a = *(const uint4*)(aptr + (s + 1) * 32);
            w = *(const uint4*)(wptr + (s + 1) * 32);
        }
        bf16x8 af = *(bf16x8*)&Al[buf][(hi * 64 + wv * 16 + lo) * 8];
        bf16x8 b0 = *(bf16x8*)&Wl[buf][(hi * 64 + 0 + lo) * 8];
        bf16x8 b1 = *(bf16x8*)&Wl[buf][(hi * 64 + 16 + lo) * 8];
        bf16x8 b2 = *(bf16x8*)&Wl[buf][(hi * 64 + 32 + lo) * 8];
        bf16x8 b3 = *(bf16x8*)&Wl[buf][(hi * 64 + 48 + lo) * 8];
        acc0 = __builtin_amdgcn_mfma_f32_16x16x32_bf16(af, b0, acc0, 0, 0, 0);
        acc1 = __builtin_amdgcn_mfma_f32_16x16x32_bf16(af, b1, acc1, 0, 0, 0);
        acc2 = __builtin_amdgcn_mfma_f32_16x16x32_bf16(af, b2, acc2, 0, 0, 0);
        acc3 = __builtin_amdgcn_mfma_f32_16x16x32_bf16(af, b3, acc3, 0, 0, 0);
    }

    float bv0 = bias ? bias[bn + 0 + lo] : 0.0f;
    float bv1 = bias ? bias[bn + 16 + lo] : 0.0f;
    float bv2 = bias ? bias[bn + 32 + lo] : 0.0f;
    float bv3 = bias ? bias[bn + 48 + lo] : 0.0f;
#pragma unroll
    for (int r = 0; r < 4; ++r) {
        size_t rw = (size_t)(bm + wv * 16 + hi * 4 + r) * 256 + bn;
        float v0 = acc0[r] + bv0, v1 = acc1[r] + bv1, v2 = acc2[r] + bv2, v3 = acc3[r] + bv3;
        if (act == 2) { v0 = gelu_f(v0); v1 = gelu_f(v1); v2 = gelu_f(v2); v3 = gelu_f(v3); }
        C[rw + 0 + lo] = v0;
        C[rw + 16 + lo] = v1;
        C[rw + 32 + lo] = v2;
        C[rw + 48 + lo] = v3;
    }
}

// ---------------- attention: K staged in bf16 LDS (coalesced), wave per (head, query) ----------------
__global__ __launch_bounds__(256) void attn_k(const float* __restrict__ qkv,
                                              ushort* __restrict__ ob) {
    __shared__ ushort kl[512 * 34];   // 34816 B, row stride 34 (17 dwords: bank-spread)
    __shared__ float sc[4][512];      // 8192 B
    int t = threadIdx.x;
    int h = blockIdx.y;

    {   // coalesced K staging: 4 threads per row read contiguous 128B, pack to bf16
        int row = t >> 2;
        const int q8 = (t & 3) * 8;
#pragma unroll
        for (int it = 0; it < 8; ++it, row += 64) {
            const float* src = qkv + (size_t)row * 768 + 256 + h * 32 + q8;
            float4 a = *(const float4*)src;
            float4 b = *(const float4*)(src + 4);
            *(uint4*)&kl[row * 34 + q8] = pack_bf8(a, b);
        }
    }
    __syncthreads();

    int w = t >> 6, lane = t & 63;
    int q = blockIdx.x * 4 + w;
    const float* qptr = qkv + (size_t)q * 768 + h * 32;
    const float* vbase = qkv + 512 + h * 32;
    float qv[32];
#pragma unroll
    for (int d = 0; d < 32; d += 4) {
        float4 f = *(const float4*)(qptr + d);
        qv[d] = f.x; qv[d + 1] = f.y; qv[d + 2] = f.z; qv[d + 3] = f.w;
    }
    float mx = -1e30f;
    for (int k = lane; k < 512; k += 64) {
        const ushort* kp = &kl[k * 34];
        uint4 r0 = *(const uint4*)kp;
        uint4 r1 = *(const uint4*)(kp + 8);
        uint4 r2 = *(const uint4*)(kp + 16);
        uint4 r3 = *(const uint4*)(kp + 24);
        float s = 0.0f;
        s = fmaf(qv[0],  blo(r0.x), s); s = fmaf(qv[1],  bhi(r0.x), s);
        s = fmaf(qv[2],  blo(r0.y), s); s = fmaf(qv[3],  bhi(r0.y), s);
        s = fmaf(qv[4],  blo(r0.z), s); s = fmaf(qv[5],  bhi(r0.z), s);
        s = fmaf(qv[6],  blo(r0.w), s); s = fmaf(qv[7],  bhi(r0.w), s);
        s = fmaf(qv[8],  blo(r1.x), s); s = fmaf(qv[9],  bhi(r1.x), s);
        s = fmaf(qv[10], blo(r1.y), s); s = fmaf(qv[11], bhi(r1.y), s);
        s = fmaf(qv[12], blo(r1.z), s); s = fmaf(qv[13], bhi(r1.z), s);
        s = fmaf(qv[14], blo(r1.w), s); s = fmaf(qv[15], bhi(r1.w), s);
        s = fmaf(qv[16], blo(r2.x), s); s = fmaf(qv[17], bhi(r2.x), s);
        s = fmaf(qv[18], blo(r2.y), s); s = fmaf(qv[19], bhi(r2.y), s);
        s = fmaf(qv[20], blo(r2.z), s); s = fmaf(qv[21], bhi(r2.z), s);
        s = fmaf(qv[22], blo(r2.w), s); s = fmaf(qv[23], bhi(r2.w), s);
        s = fmaf(qv[24], blo(r3.x), s); s = fmaf(qv[25], bhi(r3.x), s);
        s = fmaf(qv[26], blo(r3.y), s); s = fmaf(qv[27], bhi(r3.y), s);
        s = fmaf(qv[28], blo(r3.z), s); s = fmaf(qv[29], bhi(r3.z), s);
        s = fmaf(qv[30], blo(r3.w), s); s = fmaf(qv[31], bhi(r3.w), s);
        s *= 0.17677669529663687f;  // 1/sqrt(32)
        sc[w][k] = s;
        mx = fmaxf(mx, s);
    }
    mx = wave_max(mx);
    float sum = 0.0f;
    for (int k = lane; k < 512; k += 64) {
        float e = expf(sc[w][k] - mx);
        sc[w][k] = e;
        sum += e;
    }
    sum = wave_sum(sum);
    float inv = 1.0f / sum;
    __syncthreads();
    int d = lane & 31, half = lane >> 5;
    const float* vp = vbase + d;
    const int kb = half * 256;
    float a0 = 0.f, a1 = 0.f, a2 = 0.f, a3 = 0.f;
    float a4 = 0.f, a5 = 0.f, a6 = 0.f, a7 = 0.f;
    for (int k = kb; k < kb + 256; k += 8) {
        float4 p0 = *(const float4*)&sc[w][k];
        float4 p1 = *(const float4*)&sc[w][k + 4];
        a0 = fmaf(p0.x, vp[(size_t)(k + 0) * 768], a0);
        a1 = fmaf(p0.y, vp[(size_t)(k + 1) * 768], a1);
        a2 = fmaf(p0.z, vp[(size_t)(k + 2) * 768], a2);
        a3 = fmaf(p0.w, vp[(size_t)(k + 3) * 768], a3);
        a4 = fmaf(p1.x, vp[(size_t)(k + 4) * 768], a4);
        a5 = fmaf(p1.y, vp[(size_t)(k + 5) * 768], a5);
        a6 = fmaf(p1.z, vp[(size_t)(k + 6) * 768], a6);
        a7 = fmaf(p1.w, vp[(size_t)(k + 7) * 768], a7);
    }
    float accv = ((a0 + a1) + (a2 + a3)) + ((a4 + a5) + (a6 + a7));
    accv += __shfl_down(accv, 32);
    if (lane < 32) ob[(size_t)q * 256 + h * 32 + d] = f2bfu(accv * inv);
}

// ---------------- residual + LayerNorm (single y) ----------------
__global__ void ln_res_k(float* __restrict__ x, const float* __restrict__ y,
                         const float* __restrict__ g, const float* __restrict__ b,
                         size_t goff, ushort* __restrict__ xb) {
    int row = blockIdx.x, t = threadIdx.x;
    __shared__ float red[8];
    float v = x[row * 256 + t] + y[row * 256 + t];
    float s = wave_sum(v);
    if ((t & 63) == 0) red[t >> 6] = s;
    __syncthreads();
    float mean = (red[0] + red[1] + red[2] + red[3]) * (1.0f / 256.0f);
    float d = v - mean;
    float s2 = wave_sum(d * d);
    if ((t & 63) == 0) red[4 + (t >> 6)] = s2;
    __syncthreads();
    float var = (red[4] + red[5] + red[6] + red[7]) * (1.0f / 256.0f);
    float res = d * rsqrtf(var + 1e-5f) * g[goff + t] + b[goff + t];
    x[row * 256 + t] = res;
    xb[row * 256 + t] = f2bfu(res);
}

// ---------------- alpha head ----------------
__global__ void alpha_k(const float* __restrict__ t1, const float* __restrict__ aW2,
                        const float* __restrict__ ab2, float* __restrict__ alphaf,
                        float* __restrict__ out_alpha) {
    int t = threadIdx.x, w = t >> 6, lane = t & 63;
    int n = blockIdx.x * 4 + w;
    const float* r = t1 + (size_t)n * 256;
    float s = 0.0f;
    for (int d = lane; d < 256; d += 64) s = fmaf(r[d], aW2[d], s);
    s = wave_sum(s);
    if (lane == 0) {
        float z = s + ab2[0];
        float a = 1.0f / (1.0f + expf(-z));
        float al = 1.2f + 2.3f * a;
        alphaf[n] = al;
        out_alpha[n] = al;
    }
}

// ---------------- CSOC kernel attention ----------------
__global__ void csock_k(const float* __restrict__ x, const float* __restrict__ alphaf,
                        float* __restrict__ latent, float* __restrict__ out_latent,
                        ushort* __restrict__ latentb) {
    int i = blockIdx.x, t = threadIdx.x;
    __shared__ float wgt[512];
    __shared__ float red[4];
    float ai = alphaf[i];
    float lsum = 0.0f;
    for (int j = t; j < 512; j += 256) {
        float r = fabsf((float)(i - j)) + 1e-4f;
        float ap = 0.5f * (ai + alphaf[j]);
        float wv = powf(r, -ap) * expf(-r * 0.1f);
        wgt[j] = wv;
        lsum += wv;
    }
    float s = wave_sum(lsum);
    if ((t & 63) == 0) red[t >> 6] = s;
    __syncthreads();
    float S = red[0] + red[1] + red[2] + red[3] + 1e-8f;
    float acc = 0.0f;
    for (int j = 0; j < 512; ++j) acc = fmaf(wgt[j], x[(size_t)j * 256 + t], acc);
    float res = acc / S;
    latent[(size_t)i * 256 + t] = res;
    out_latent[(size_t)i * 256 + t] = res;
    latentb[(size_t)i * 256 + t] = f2bfu(res);
}

// ---------------- merged finals: contact (512 blk) + torsion (128 blk) + diff (6 blk) ----------------
__global__ __launch_bounds__(256) void finals_k(const float* __restrict__ h,
                                                const float* __restrict__ t1t,
                                                const float* __restrict__ latentf,
                                                const float* __restrict__ tW2,
                                                const float* __restrict__ tb2,
                                                const float* __restrict__ pW,
                                                const float* __restrict__ pb,
                                                const float* __restrict__ noise,
                                                float* __restrict__ out_contact,
                                                float* __restrict__ phi,
                                                float* __restrict__ psi,
                                                float* __restrict__ outc) {
    const int blk = blockIdx.x;
    const int t = threadIdx.x;
    if (blk < 512) {
        int i = blk;
        __shared__ float hi_s[256];
        hi_s[t] = h[(size_t)i * 256 + t];
        __syncthreads();
        for (int j = t; j < 512; j += 256) {
            const float* hj = h + (size_t)j * 256;
            float s = 0.0f;
#pragma unroll 4
            for (int d = 0; d < 256; d += 4) {
                float4 a = *(const float4*)&hi_s[d];
                float4 b = *(const float4*)&hj[d];
                s = fmaf(a.x, b.x, s); s = fmaf(a.y, b.y, s);
                s = fmaf(a.z, b.z, s); s = fmaf(a.w, b.w, s);
            }
            out_contact[(size_t)i * 512 + j] = 1.0f / (1.0f + expf(-s));
        }
    } else if (blk < 640) {
        int w = t >> 6, lane = t & 63;
        int n = (blk - 512) * 4 + w;
        const float* r = t1t + (size_t)n * 256;
        float s0 = 0.0f, s1 = 0.0f;
        for (int d = lane; d < 256; d += 64) {
            float v = r[d];
            s0 = fmaf(v, tW2[d], s0);
            s1 = fmaf(v, tW2[256 + d], s1);
        }
        s0 = wave_sum(s0);
        s1 = wave_sum(s1);
        if (lane == 0) {
            phi[n] = tanhf(s0 + tb2[0]) * 3.14159265358979323846f;
            psi[n] = tanhf(s1 + tb2[1]) * 3.14159265358979323846f;
        }
    } else {
        int idx = (blk - 640) * 256 + t;
        if (idx >= 512 * 3) return;
        int n = idx / 3, a = idx % 3;
        const float* r = latentf + (size_t)n * 256;
        float s = pb[a];
        for (int d = 0; d < 256; ++d) s = fmaf(r[d], pW[(size_t)a * 256 + d], s);
        float c = noise[idx];
#pragma unroll
        for (int st = 9; st >= 0; --st) {
            float at = (float)(st + 1) * 0.1f;
            c = at * c + (1.0f - at) * s;
        }
        outc[idx] = c;
    }
}

// ---------------- distogram v5 (best): exact gelu -> A-fragments, grid 512, no main-loop barriers ----------------
__global__ __launch_bounds__(256) void disto_k(const float* __restrict__ U,
                                               const float* __restrict__ V,
                                               const float* __restrict__ dW2,
                                               const float* __restrict__ db2,
                                               float* __restrict__ out) {
    __shared__ short w2l[32 * 64 * 8];   // 32KB
    const int t = threadIdx.x;
    const int i = blockIdx.x;

    {   // stage dW2 -> bf16 LDS (once per block)
        const int brow = t >> 2, dq = t & 3;
#pragma unroll
        for (int c = 0; c < 8; ++c) {
            int dblk = dq * 8 + c;
            int d0 = dblk * 8;
            float4 w0 = *(const float4*)&dW2[(size_t)brow * 256 + d0];
            float4 w1 = *(const float4*)&dW2[(size_t)brow * 256 + d0 + 4];
            *(uint4*)&w2l[(dblk * 64 + brow) * 8] = pack_bf8(w0, w1);
        }
    }
    __syncthreads();

    const int wv = t >> 6, lane = t & 63;
    const int lo = lane & 15, hi = lane >> 4;

    float4 uf0[8], uf1[8];
#pragma unroll
    for (int kk = 0; kk < 8; ++kk) {
        uf0[kk] = *(const float4*)&U[(size_t)i * 256 + kk * 32 + hi * 8];
        uf1[kk] = *(const float4*)&U[(size_t)i * 256 + kk * 32 + hi * 8 + 4];
    }
    float dbv[4];
#pragma unroll
    for (int nt = 0; nt < 4; ++nt) dbv[nt] = db2[nt * 16 + lo];

    for (int p = 0; p < 8; ++p) {
        const int j = p * 64 + wv * 16 + lo;
        const float* vrow = V + (size_t)j * 256;
        f32x4 acc0 = {0.f, 0.f, 0.f, 0.f}, acc1 = acc0, acc2 = acc0, acc3 = acc0;
#pragma unroll
        for (int kk = 0; kk < 8; ++kk) {
            float4 v0 = *(const float4*)&vrow[kk * 32 + hi * 8];
            float4 v1 = *(const float4*)&vrow[kk * 32 + hi * 8 + 4];
            float4 h0, h1;
            h0.x = gelu_f(uf0[kk].x + v0.x); h0.y = gelu_f(uf0[kk].y + v0.y);
            h0.z = gelu_f(uf0[kk].z + v0.z); h0.w = gelu_f(uf0[kk].w + v0.w);
            h1.x = gelu_f(uf1[kk].x + v1.x); h1.y = gelu_f(uf1[kk].y + v1.y);
            h1.z = gelu_f(uf1[kk].z + v1.z); h1.w = gelu_f(uf1[kk].w + v1.w);
            uint4 ap = pack_bf8(h0, h1);
            bf16x8 a = *(bf16x8*)&ap;
            int db = kk * 4 + hi;
            bf16x8 b0 = *(bf16x8*)&w2l[(db * 64 + 0 + lo) * 8];
            bf16x8 b1 = *(bf16x8*)&w2l[(db * 64 + 16 + lo) * 8];
            bf16x8 b2 = *(bf16x8*)&w2l[(db * 64 + 32 + lo) * 8];
            bf16x8 b3 = *(bf16x8*)&w2l[(db * 64 + 48 + lo) * 8];
            acc0 = __builtin_amdgcn_mfma_f32_16x16x32_bf16(a, b0, acc0, 0, 0, 0);
            acc1 = __builtin_amdgcn_mfma_f32_16x16x32_bf16(a, b1, acc1, 0, 0, 0);
            acc2 = __builtin_amdgcn_mfma_f32_16x16x32_bf16(a, b2, acc2, 0, 0, 0);
            acc3 = __builtin_amdgcn_mfma_f32_16x16x32_bf16(a, b3, acc3, 0, 0, 0);
        }
#pragma unroll
        for (int r = 0; r < 4; ++r) {
            size_t jg = (size_t)i * 512 + p * 64 + wv * 16 + hi * 4 + r;
            out[jg * 64 + 0 + lo] = acc0[r] + dbv[0];
            out[jg * 64 + 16 + lo] = acc1[r] + dbv[1];
            out[jg * 64 + 32 + lo] = acc2[r] + dbv[2];
            out[jg * 64 + 48 + lo] = acc3[r] + dbv[3];
        }
    }
}

extern "C" void kernel_launch(void* const* d_in, const int* in_sizes, int n_in,
                              void* d_out, int out_size, void* d_ws, size_t ws_size,
                              hipStream_t stream) {
    const int* tokens  = (const int*)d_in[0];
    const float* noise = (const float*)d_in[1];
    const float* emb   = (const float*)d_in[2];
    const float* Wqkv  = (const float*)d_in[3];
    const float* bqkv  = (const float*)d_in[4];
    const float* Wo    = (const float*)d_in[5];
    const float* bo    = (const float*)d_in[6];
    const float* ln1_g = (const float*)d_in[7];
    const float* ln1_b = (const float*)d_in[8];
    const float* W1    = (const float*)d_in[9];
    const float* b1    = (const float*)d_in[10];
    const float* W2    = (const float*)d_in[11];
    const float* b2    = (const float*)d_in[12];
    const float* ln2_g = (const float*)d_in[13];
    const float* ln2_b = (const float*)d_in[14];
    const float* aW1   = (const float*)d_in[15];
    const float* ab1   = (const float*)d_in[16];
    const float* aW2   = (const float*)d_in[17];
    const float* ab2   = (const float*)d_in[18];
    const float* cW    = (const float*)d_in[19];
    const float* cb    = (const float*)d_in[20];
    const float* dW1   = (const float*)d_in[21];
    const float* db1   = (const float*)d_in[22];
    const float* dW2   = (const float*)d_in[23];
    const float* db2   = (const float*)d_in[24];
    const float* tW1   = (const float*)d_in[25];
    const float* tb1   = (const float*)d_in[26];
    const float* tW2   = (const float*)d_in[27];
    const float* tb2   = (const float*)d_in[28];
    const float* pW    = (const float*)d_in[29];
    const float* pb    = (const float*)d_in[30];

    // output layout (FLOAT32, concatenated in return order)
    float* out         = (float*)d_out;
    float* out_latent  = out;               // 131072
    float* out_alpha   = out + 131072;      // 512
    float* out_contact = out + 131584;      // 262144
    float* out_disto   = out + 393728;      // 16777216
    float* out_phi     = out + 17170944;    // 512
    float* out_psi     = out + 17171456;    // 512
    float* out_c       = out + 17171968;    // 1536

    // transient scratch inside out_disto; disto_k runs LAST.
    float* scratch = out_disto;
    float* x    = scratch;             // 131072 f32
    float* qkv  = scratch + 131072;    // 393216 f32
    float* t1t  = scratch + 655360;    // 131072 f32 (torsion t1)
    float* y    = scratch + 1179648;   // 131072 f32
    float* hbuf = scratch + 1310720;   // 131072 f32
    float* t1a  = scratch + 1441792;   // 131072 f32 (alpha t1)
    ushort* wb      = (ushort*)(scratch + 2000000);  // 3473408 bf16
    ushort* xb      = (ushort*)(scratch + 3740000);  // 131072 bf16
    ushort* ob      = (ushort*)(scratch + 3810000);  // 131072 bf16
    ushort* ffhb    = (ushort*)(scratch + 3880000);  // 524288 bf16
    ushort* latentb = (ushort*)(scratch + 4150000);  // 131072 bf16
    float* yp   = scratch + 4300000;   // 524288 f32 (4 split-K slices)

    // persistent across disto_k: keep in d_ws
    float* latentf = (float*)d_ws;      // 131072
    float* U       = latentf + 131072;  // 131072
    float* Vv      = U + 131072;        // 131072
    float* alphaf  = Vv + 131072;       // 512

    prep_k<<<2208, 256, 0, stream>>>(Wqkv, Wo, W1, W2, aW1, cW, dW1, tW1, wb,
                                     tokens, emb, x, xb);

    for (int l = 0; l < 4; ++l) {
        gemm_bf<0, 0><<<dim3(12, 8), 256, 0, stream>>>(xb, wb, bqkv, qkv, nullptr,
                                                       768, 256, 256, 256, 0,
                                                       OFF_QKV + (size_t)l * 196608, (size_t)l * 768);
        attn_k<<<dim3(128, 8), 256, 0, stream>>>(qkv, ob);
        gemm_bf<0, 0><<<dim3(4, 8), 256, 0, stream>>>(ob, wb, bo, y, nullptr,
                                                      256, 256, 256, 256, 0,
                                                      OFF_WO + (size_t)l * 65536, (size_t)l * 256);
        ln_res_k<<<512, 256, 0, stream>>>(x, y, ln1_g, ln1_b, (size_t)l * 256, xb);
        gemm_bf<1, 1><<<dim3(16, 8), 256, 0, stream>>>(xb, wb, b1, nullptr, ffhb,
                                                       1024, 256, 256, 256, 0,
                                                       OFF_W1 + (size_t)l * 262144, (size_t)l * 1024);
        ffn2_splitk<<<dim3(4, 8, 4), 256, 0, stream>>>(ffhb, wb, yp,
                                                       OFF_W2 + (size_t)l * 262144);
        ln_res4_k<<<512, 256, 0, stream>>>(x, yp, b2, (size_t)l * 256,
                                           ln2_g, ln2_b, (size_t)l * 256, xb);
    }

    // alpha head: t1a = gelu(x.aW1^T + ab1) via MFMA
    gemm_bf<2, 0><<<dim3(4, 8), 256, 0, stream>>>(xb, wb, ab1, t1a, nullptr,
                                                  256, 256, 256, 256, 0, OFF_AW1, 0);
    alpha_k<<<128, 256, 0, stream>>>(t1a, aW2, ab2, alphaf, out_alpha);

    // CSOC kernel attention -> latent (f32 + bf16)
    csock_k<<<512, 256, 0, stream>>>(x, alphaf, latentf, out_latent, latentb);

    // batched head GEMMs: contact-h, U, V, torsion-t1
    heads_k<<<dim3(4, 8, 4), 256, 0, stream>>>(latentb, wb, cb, db1, tb1,
                                               hbuf, U, Vv, t1t);

    // merged contact + torsion + diffusion
    finals_k<<<646, 256, 0, stream>>>(hbuf, t1t, latentf, tW2, tb2, pW, pb, noise,
                                      out_contact, out_phi, out_psi, out_c);

    // distogram LAST: overwrites the scratch region with the real output
    disto_k<<<512, 256, 0, stream>>>(U, Vv, dW2, db2, out_disto);
}